// Round 1
// baseline (474.674 us; speedup 1.0000x reference)
//
#include <hip/hip_runtime.h>

typedef __attribute__((ext_vector_type(4))) float   f32x4;
typedef __attribute__((ext_vector_type(4))) float   float4v;
typedef __attribute__((ext_vector_type(8))) __bf16  bf16x8;
typedef unsigned short u16;
typedef __attribute__((ext_vector_type(8))) unsigned short u16x8;
typedef __attribute__((ext_vector_type(4))) unsigned short u16x4;

__device__ __forceinline__ u16 f2bf(float f) {
  unsigned u = __builtin_bit_cast(unsigned, f);
  u += 0x7fffu + ((u >> 16) & 1u);
  return (u16)(u >> 16);
}
__device__ __forceinline__ float bf2f(u16 h) {
  unsigned u = ((unsigned)h) << 16;
  return __builtin_bit_cast(float, u);
}

#define BM 128
#define BN 128
#define BK 32
#define LDT 40   // padded LDS row stride in u16 (80 B) -> conflict-spread ds_read_b128

// EPI: 0 = plain bf16 store, 1 = K normal + V transposed (proj KV), 2 = scores (scale+mask), 3 = relu f32
template<int AF32, int EPI>
__global__ __launch_bounds__(256)
void gemm_k(const void* __restrict__ Ap, const u16* __restrict__ Bp,
            void* __restrict__ Cp, void* __restrict__ Cp2,
            const int* __restrict__ maskp,
            int K, long sA, long sB, long sC, long sM, int ldc, float scale)
{
  __shared__ u16 As[2][BM * LDT];
  __shared__ u16 Bs[2][BM * LDT];

  const int t  = threadIdx.x;
  const int z  = blockIdx.z;
  const int n0 = blockIdx.x * BN;
  const int m0 = blockIdx.y * BM;
  const int KT = K / BK;

  const u16* Bb = Bp + (long)z * sB;

  f32x4 acc[4][4];
#pragma unroll
  for (int i = 0; i < 4; i++)
#pragma unroll
    for (int j = 0; j < 4; j++) acc[i][j] = f32x4{0.f, 0.f, 0.f, 0.f};

  const int w = t >> 6, lane = t & 63;
  const int m0w = (w >> 1) * 64, n0w = (w & 1) * 64;
  const int lr = lane & 15, lc = lane >> 4;

  float4v fa[4];
  u16x8   ua[2];
  u16x8   ub[2];

  auto loadA = [&](int kt) {
    if constexpr (AF32) {
      const float* A = (const float*)Ap + (long)z * sA;
#pragma unroll
      for (int i = 0; i < 4; i++) {
        int idx = i * 256 + t, r = idx >> 3, c4 = idx & 7;
        fa[i] = *(const float4v*)(A + (long)(m0 + r) * K + kt * BK + c4 * 4);
      }
    } else {
      const u16* A = (const u16*)Ap + (long)z * sA;
#pragma unroll
      for (int i = 0; i < 2; i++) {
        int idx = i * 256 + t, r = idx >> 2, c8 = idx & 3;
        ua[i] = *(const u16x8*)(A + (long)(m0 + r) * K + kt * BK + c8 * 8);
      }
    }
  };
  auto loadB = [&](int kt) {
#pragma unroll
    for (int i = 0; i < 2; i++) {
      int idx = i * 256 + t, r = idx >> 2, c8 = idx & 3;
      ub[i] = *(const u16x8*)(Bb + (long)(n0 + r) * K + kt * BK + c8 * 8);
    }
  };
  auto writeAB = [&](int buf) {
    if constexpr (AF32) {
#pragma unroll
      for (int i = 0; i < 4; i++) {
        int idx = i * 256 + t, r = idx >> 3, c4 = idx & 7;
        u16x4 h;
#pragma unroll
        for (int jj = 0; jj < 4; jj++) h[jj] = f2bf(fa[i][jj]);
        *(u16x4*)&As[buf][r * LDT + c4 * 4] = h;
      }
    } else {
#pragma unroll
      for (int i = 0; i < 2; i++) {
        int idx = i * 256 + t, r = idx >> 2, c8 = idx & 3;
        *(u16x8*)&As[buf][r * LDT + c8 * 8] = ua[i];
      }
    }
#pragma unroll
    for (int i = 0; i < 2; i++) {
      int idx = i * 256 + t, r = idx >> 2, c8 = idx & 3;
      *(u16x8*)&Bs[buf][r * LDT + c8 * 8] = ub[i];
    }
  };
  auto compute = [&](int buf) {
    bf16x8 af[4], bfr[4];
#pragma unroll
    for (int f = 0; f < 4; f++) {
      af[f]  = __builtin_bit_cast(bf16x8, *(const u16x8*)&As[buf][(m0w + f * 16 + lr) * LDT + lc * 8]);
      bfr[f] = __builtin_bit_cast(bf16x8, *(const u16x8*)&Bs[buf][(n0w + f * 16 + lr) * LDT + lc * 8]);
    }
#pragma unroll
    for (int i = 0; i < 4; i++)
#pragma unroll
      for (int j = 0; j < 4; j++)
        acc[i][j] = __builtin_amdgcn_mfma_f32_16x16x32_bf16(af[i], bfr[j], acc[i][j], 0, 0, 0);
  };

  loadA(0); loadB(0);
  writeAB(0);
  __syncthreads();
  int cur = 0;
  for (int kt = 1; kt < KT; ++kt) {
    loadA(kt); loadB(kt);   // global -> regs (latency hides under MFMA)
    compute(cur);
    writeAB(cur ^ 1);
    __syncthreads();
    cur ^= 1;
  }
  compute(cur);

  // -------- epilogue --------
#pragma unroll
  for (int i = 0; i < 4; i++) {
#pragma unroll
    for (int j = 0; j < 4; j++) {
      const int mb = m0 + m0w + i * 16 + lc * 4;
      const int n  = n0 + n0w + j * 16 + lr;
      if constexpr (EPI == 0) {
        u16* C = (u16*)Cp + (long)z * sC;
#pragma unroll
        for (int ii = 0; ii < 4; ii++)
          C[(long)(mb + ii) * ldc + n] = f2bf(acc[i][j][ii]);
      } else if constexpr (EPI == 1) {
        if (n < 512) {
          u16* C = (u16*)Cp;
#pragma unroll
          for (int ii = 0; ii < 4; ii++)
            C[(long)(mb + ii) * 512 + n] = f2bf(acc[i][j][ii]);
        } else {
          u16* C2 = (u16*)Cp2;
          const int b = mb >> 11, kv = mb & 2047, d = n - 512;
          u16x4 h;
#pragma unroll
          for (int ii = 0; ii < 4; ii++) h[ii] = f2bf(acc[i][j][ii]);
          *(u16x4*)(C2 + ((long)(b * 512 + d)) * 2048 + kv) = h;
        }
      } else if constexpr (EPI == 2) {
        const int* mk = maskp + (long)z * sM;
        u16* C = (u16*)Cp + (long)z * sC;
        const float bias = mk[n] ? 0.f : -1e10f;
#pragma unroll
        for (int ii = 0; ii < 4; ii++)
          C[(long)(mb + ii) * ldc + n] = f2bf(acc[i][j][ii] * scale + bias);
      } else {
        float* C = (float*)Cp + (long)z * sC;
#pragma unroll
        for (int ii = 0; ii < 4; ii++)
          C[(long)(mb + ii) * ldc + n] = fmaxf(acc[i][j][ii], 0.f);
      }
    }
  }
}

// convert + concat [Wq;Wk;Wv] f32 [3*512,512] -> bf16
__global__ __launch_bounds__(256)
void wconv_k(const float* __restrict__ Wq, const float* __restrict__ Wk,
             const float* __restrict__ Wv, u16* __restrict__ Wb)
{
  long i4 = (long)blockIdx.x * 256 + threadIdx.x;
  long e  = i4 * 4;
  const float* W = (e < 262144) ? Wq : (e < 524288 ? Wk : Wv);
  long off = e & 262143;
  float4v f = *(const float4v*)(W + off);
  u16x4 h;
#pragma unroll
  for (int j = 0; j < 4; j++) h[j] = f2bf(f[j]);
  *(u16x4*)(Wb + e) = h;
}

// in-place row softmax over 2048 bf16 logits
__global__ __launch_bounds__(256)
void softmax_k(u16* __restrict__ S)
{
  const long row = blockIdx.x;
  const int  t   = threadIdx.x;
  u16* R = S + row * 2048;
  u16x8 v = *(const u16x8*)(R + t * 8);
  float f[8];
#pragma unroll
  for (int j = 0; j < 8; j++) f[j] = bf2f(v[j]);
  float m = f[0];
#pragma unroll
  for (int j = 1; j < 8; j++) m = fmaxf(m, f[j]);
#pragma unroll
  for (int off = 32; off > 0; off >>= 1) m = fmaxf(m, __shfl_xor(m, off));
  __shared__ float red[4], red2[4];
  const int w = t >> 6;
  if ((t & 63) == 0) red[w] = m;
  __syncthreads();
  m = fmaxf(fmaxf(red[0], red[1]), fmaxf(red[2], red[3]));
  float e[8], s = 0.f;
#pragma unroll
  for (int j = 0; j < 8; j++) { e[j] = __expf(f[j] - m); s += e[j]; }
#pragma unroll
  for (int off = 32; off > 0; off >>= 1) s += __shfl_xor(s, off);
  if ((t & 63) == 0) red2[w] = s;
  __syncthreads();
  s = red2[0] + red2[1] + red2[2] + red2[3];
  const float inv = 1.f / s;
  u16x8 o;
#pragma unroll
  for (int j = 0; j < 8; j++) o[j] = f2bf(e[j] * inv);
  *(u16x8*)(R + t * 8) = o;
}

extern "C" void kernel_launch(void* const* d_in, const int* in_sizes, int n_in,
                              void* d_out, int out_size, void* d_ws, size_t ws_size,
                              hipStream_t stream)
{
  const float* mf   = (const float*)d_in[0];   // [64,128,512]
  const float* x    = (const float*)d_in[1];   // [64,2048,512]
  const int*   mask = (const int*)d_in[2];     // [64,2048]
  const float* Wq   = (const float*)d_in[3];
  const float* Wk   = (const float*)d_in[4];
  const float* Wv   = (const float*)d_in[5];
  float* out = (float*)d_out;

  u16* ws = (u16*)d_ws;
  u16* Wb = ws;                          // 1536*512           = 786432
  u16* Qb = Wb + 786432;                 // 8192*512           = 4194304
  u16* dyn = Qb + 4194304;

  // chunk batches so scratch fits: per-batch = K(1M) + Vt(1M) + S(256K) u16 = 4.5 MiB
  const size_t fixed_b = (size_t)(786432 + 4194304) * 2;
  int CB = 64;
  while (CB > 1 && fixed_b + (size_t)CB * 4718592ull > ws_size) CB >>= 1;

  u16* Kc  = dyn;                              // [CB*2048, 512]
  u16* Vtc = Kc + (size_t)CB * 2048 * 512;     // [CB, 512, 2048]  (V transposed)
  u16* Sc  = Vtc + (size_t)CB * 512 * 2048;    // [CB, 128, 2048]

  const float scale = 0.044194173824159216f;   // 1/sqrt(512)

  wconv_k<<<768, 256, 0, stream>>>(Wq, Wk, Wv, Wb);

  // Q projection: M=8192, N=512, K=512, A f32
  gemm_k<1, 0><<<dim3(4, 64, 1), 256, 0, stream>>>(
      mf, Wb, Qb, nullptr, nullptr, 512, 0, 0, 0, 0, 512, 1.f);

  for (int bc = 0; bc < 64; bc += CB) {
    const float* xc = x + (long)bc * 2048 * 512;
    // fused K+V projection: M=CB*2048, N=1024 (cols 0-511 -> K, 512-1023 -> V transposed)
    gemm_k<1, 1><<<dim3(8, CB * 16, 1), 256, 0, stream>>>(
        xc, Wb + 262144, Kc, Vtc, nullptr, 512, 0, 0, 0, 0, 512, 1.f);
    // scores: per batch z: S[q,kv] = (Q Kt)*scale - (1-mask)*1e10  (bf16)
    gemm_k<0, 2><<<dim3(16, 1, CB), 256, 0, stream>>>(
        Qb + (long)bc * 65536, Kc, Sc, nullptr, mask + (long)bc * 2048,
        512, 65536, 1048576, 262144, 2048, 2048, scale);
    // softmax rows (in place)
    softmax_k<<<CB * 128, 256, 0, stream>>>(Sc);
    // PV: out[q,d] = relu(P Vt), K=2048, f32 out
    gemm_k<0, 3><<<dim3(4, 1, CB), 256, 0, stream>>>(
        Sc, Vtc, out + (long)bc * 65536, nullptr, nullptr,
        2048, 262144, 1048576, 65536, 0, 512, 1.f);
  }
}

// Round 2
// 474.393 us; speedup vs baseline: 1.0006x; 1.0006x over previous
//
#include <hip/hip_runtime.h>

typedef __attribute__((ext_vector_type(4))) float   f32x4;
typedef __attribute__((ext_vector_type(8))) __bf16  bf16x8;
typedef unsigned short u16;
typedef __attribute__((ext_vector_type(8))) unsigned short u16x8;
typedef __attribute__((ext_vector_type(4))) unsigned short u16x4;

__device__ __forceinline__ u16 f2bf(float f) {
  unsigned u = __builtin_bit_cast(unsigned, f);
  u += 0x7fffu + ((u >> 16) & 1u);
  return (u16)(u >> 16);
}
__device__ __forceinline__ float bf2f(u16 h) {
  unsigned u = ((unsigned)h) << 16;
  return __builtin_bit_cast(float, u);
}

__device__ __forceinline__ void gld16(const void* g, void* l) {
  __builtin_amdgcn_global_load_lds(
      (const __attribute__((address_space(1))) void*)g,
      (__attribute__((address_space(3))) void*)l, 16, 0, 0);
}

// C[m,n] = sum_k A[m,k] * B[n,k]   (B stored K-major, i.e. B^T input)
// 128x128 tile, BK=32, 4 waves (2x2 of 64x64), 16x16x32 bf16 MFMA.
// Staging: global_load_lds width 16, LINEAR LDS dest; bank-conflict-free
// fragment reads via inverse-swizzled GLOBAL source + swizzled ds_read (T2).
// AF32: A is f32 in HBM, staged raw, converted to bf16 at fragment read.
// EPI: 0 = bf16 store, 1 = K normal + V transposed, 2 = scores(scale+mask), 3 = relu f32
// SWZ: bijective XCD-contiguous tile remap (T1).
template<int AF32, int EPI, int SWZ>
__global__ __launch_bounds__(256)
void gemm_k(const void* __restrict__ Ap, const u16* __restrict__ Bp,
            void* __restrict__ Cp, void* __restrict__ Cp2,
            const int* __restrict__ maskp,
            int K, long sA, long sB, long sC, long sM, int ldc, float scale)
{
  __shared__ float Asf[2][AF32 ? 4096 : 4];   // f32 A tile 128x32
  __shared__ u16   Asb[2][AF32 ? 4 : 4096];   // bf16 A tile 128x32
  __shared__ u16   Bs [2][4096];              // bf16 B tile 128x32

  int bx = blockIdx.x, by = blockIdx.y;
  if constexpr (SWZ) {
    int nwg = gridDim.x * gridDim.y;          // must be divisible by 8
    int h = bx + gridDim.x * by;
    int q = nwg >> 3;
    int s = (h & 7) * q + (h >> 3);           // XCD h%8 gets contiguous tiles
    bx = s % gridDim.x; by = s / gridDim.x;
  }
  const int t = threadIdx.x, z = blockIdx.z;
  const int n0 = bx * 128, m0 = by * 128;
  const int KT = K / 32;
  const u16* Bb = Bp + (long)z * sB;

  const int w = t >> 6, lane = t & 63;
  const int m0w = (w >> 1) * 64, n0w = (w & 1) * 64;
  const int lr = lane & 15, lc = lane >> 4;

  f32x4 acc[4][4];
#pragma unroll
  for (int i = 0; i < 4; i++)
#pragma unroll
    for (int j = 0; j < 4; j++) acc[i][j] = f32x4{0.f, 0.f, 0.f, 0.f};

  auto stage = [&](int buf, int kt) {
    if constexpr (AF32) {
      const float* A = (const float*)Ap + (long)z * sA;
#pragma unroll
      for (int i = 0; i < 4; i++) {
        int chunk = w * 4 + i;                 // 16 chunks of 1KB
        int row = chunk * 8 + (lane >> 3);     // 8 rows (128B) per chunk
        int cc  = lane & 7;                    // 16B slot within row
        const float* g = A + (long)(m0 + row) * K + kt * 32 + ((cc ^ (row & 7)) << 2);
        gld16(g, (void*)&Asf[buf][chunk * 256]);
      }
    } else {
      const u16* A = (const u16*)Ap + (long)z * sA;
#pragma unroll
      for (int i = 0; i < 2; i++) {
        int chunk = w * 2 + i;                 // 8 chunks of 1KB
        int row = chunk * 16 + (lane >> 2);    // 16 rows (64B) per chunk
        int cc  = lane & 3;
        const u16* g = A + (long)(m0 + row) * K + kt * 32 + ((cc ^ ((row >> 1) & 3)) << 3);
        gld16(g, (void*)&Asb[buf][chunk * 512]);
      }
    }
#pragma unroll
    for (int i = 0; i < 2; i++) {
      int chunk = w * 2 + i;
      int row = chunk * 16 + (lane >> 2);
      int cc  = lane & 3;
      const u16* g = Bb + (long)(n0 + row) * K + kt * 32 + ((cc ^ ((row >> 1) & 3)) << 3);
      gld16(g, (void*)&Bs[buf][chunk * 512]);
    }
  };

  auto compute = [&](int buf) {
    bf16x8 af[4], bv[4];
#pragma unroll
    for (int f = 0; f < 4; f++) {
      const int R = m0w + f * 16 + lr;
      if constexpr (AF32) {
        f32x4 lo = *(const f32x4*)&Asf[buf][R * 32 + (((lc * 2 + 0) ^ (R & 7)) << 2)];
        f32x4 hi = *(const f32x4*)&Asf[buf][R * 32 + (((lc * 2 + 1) ^ (R & 7)) << 2)];
        bf16x8 v;
#pragma unroll
        for (int j = 0; j < 4; j++) { v[j] = (__bf16)lo[j]; v[4 + j] = (__bf16)hi[j]; }
        af[f] = v;
      } else {
        af[f] = __builtin_bit_cast(bf16x8,
            *(const u16x8*)&Asb[buf][R * 32 + ((lc ^ ((R >> 1) & 3)) << 3)]);
      }
      const int R2 = n0w + f * 16 + lr;
      bv[f] = __builtin_bit_cast(bf16x8,
          *(const u16x8*)&Bs[buf][R2 * 32 + ((lc ^ ((R2 >> 1) & 3)) << 3)]);
    }
#pragma unroll
    for (int i = 0; i < 4; i++)
#pragma unroll
      for (int j = 0; j < 4; j++)
        acc[i][j] = __builtin_amdgcn_mfma_f32_16x16x32_bf16(af[i], bv[j], acc[i][j], 0, 0, 0);
  };

  stage(0, 0);
  __syncthreads();
  int cur = 0;
  for (int kt = 1; kt < KT; ++kt) {
    stage(cur ^ 1, kt);       // async into other buffer; barrier drains vmcnt
    compute(cur);
    __syncthreads();
    cur ^= 1;
  }
  compute(cur);

  // -------- epilogue --------
#pragma unroll
  for (int i = 0; i < 4; i++) {
#pragma unroll
    for (int j = 0; j < 4; j++) {
      const int mb = m0 + m0w + i * 16 + lc * 4;
      const int n  = n0 + n0w + j * 16 + lr;
      if constexpr (EPI == 0) {
        u16* C = (u16*)Cp + (long)z * sC;
#pragma unroll
        for (int ii = 0; ii < 4; ii++)
          C[(long)(mb + ii) * ldc + n] = f2bf(acc[i][j][ii]);
      } else if constexpr (EPI == 1) {
        if (n < 512) {
          u16* C = (u16*)Cp;
#pragma unroll
          for (int ii = 0; ii < 4; ii++)
            C[(long)(mb + ii) * 512 + n] = f2bf(acc[i][j][ii]);
        } else {
          u16* C2 = (u16*)Cp2;
          const int b = mb >> 11, kv = mb & 2047, d = n - 512;
          u16x4 h;
#pragma unroll
          for (int ii = 0; ii < 4; ii++) h[ii] = f2bf(acc[i][j][ii]);
          *(u16x4*)(C2 + ((long)(b * 512 + d)) * 2048 + kv) = h;
        }
      } else if constexpr (EPI == 2) {
        const int* mk = maskp + (long)z * sM;
        u16* C = (u16*)Cp + (long)z * sC;
        const float bias = mk[n] ? 0.f : -1e10f;
#pragma unroll
        for (int ii = 0; ii < 4; ii++)
          C[(long)(mb + ii) * ldc + n] = f2bf(acc[i][j][ii] * scale + bias);
      } else {
        float* C = (float*)Cp + (long)z * sC;
#pragma unroll
        for (int ii = 0; ii < 4; ii++)
          C[(long)(mb + ii) * ldc + n] = fmaxf(acc[i][j][ii], 0.f);
      }
    }
  }
}

// convert + concat [Wq;Wk;Wv] f32 [3*512,512] -> bf16
__global__ __launch_bounds__(256)
void wconv_k(const float* __restrict__ Wq, const float* __restrict__ Wk,
             const float* __restrict__ Wv, u16* __restrict__ Wb)
{
  long i4 = (long)blockIdx.x * 256 + threadIdx.x;
  long e  = i4 * 4;
  const float* W = (e < 262144) ? Wq : (e < 524288 ? Wk : Wv);
  long off = e & 262143;
  f32x4 f = *(const f32x4*)(W + off);
  u16x4 h;
#pragma unroll
  for (int j = 0; j < 4; j++) h[j] = f2bf(f[j]);
  *(u16x4*)(Wb + e) = h;
}

// f32 -> bf16, 8 elems/thread (exact multiple)
__global__ __launch_bounds__(256)
void cvt_k(const float* __restrict__ in, u16* __restrict__ out)
{
  long i = ((long)blockIdx.x * 256 + threadIdx.x) * 8;
  f32x4 a = *(const f32x4*)(in + i);
  f32x4 b = *(const f32x4*)(in + i + 4);
  u16x8 h;
#pragma unroll
  for (int j = 0; j < 4; j++) { h[j] = f2bf(a[j]); h[4 + j] = f2bf(b[j]); }
  *(u16x8*)(out + i) = h;
}

// in-place row softmax over 2048 bf16 logits
__global__ __launch_bounds__(256)
void softmax_k(u16* __restrict__ S)
{
  const long row = blockIdx.x;
  const int  t   = threadIdx.x;
  u16* R = S + row * 2048;
  u16x8 v = *(const u16x8*)(R + t * 8);
  float f[8];
#pragma unroll
  for (int j = 0; j < 8; j++) f[j] = bf2f(v[j]);
  float m = f[0];
#pragma unroll
  for (int j = 1; j < 8; j++) m = fmaxf(m, f[j]);
#pragma unroll
  for (int off = 32; off > 0; off >>= 1) m = fmaxf(m, __shfl_xor(m, off));
  __shared__ float red[4], red2[4];
  const int w = t >> 6;
  if ((t & 63) == 0) red[w] = m;
  __syncthreads();
  m = fmaxf(fmaxf(red[0], red[1]), fmaxf(red[2], red[3]));
  float e[8], s = 0.f;
#pragma unroll
  for (int j = 0; j < 8; j++) { e[j] = __expf(f[j] - m); s += e[j]; }
#pragma unroll
  for (int off = 32; off > 0; off >>= 1) s += __shfl_xor(s, off);
  if ((t & 63) == 0) red2[w] = s;
  __syncthreads();
  s = red2[0] + red2[1] + red2[2] + red2[3];
  const float inv = 1.f / s;
  u16x8 o;
#pragma unroll
  for (int j = 0; j < 8; j++) o[j] = f2bf(e[j] * inv);
  *(u16x8*)(R + t * 8) = o;
}

extern "C" void kernel_launch(void* const* d_in, const int* in_sizes, int n_in,
                              void* d_out, int out_size, void* d_ws, size_t ws_size,
                              hipStream_t stream)
{
  const float* mf   = (const float*)d_in[0];   // [64,128,512]
  const float* x    = (const float*)d_in[1];   // [64,2048,512]
  const int*   mask = (const int*)d_in[2];     // [64,2048]
  const float* Wq   = (const float*)d_in[3];
  const float* Wk   = (const float*)d_in[4];
  const float* Wv   = (const float*)d_in[5];
  float* out = (float*)d_out;

  u16* ws  = (u16*)d_ws;
  u16* Wb  = ws;                     // 1536*512 = 786432 u16
  u16* mfb = Wb + 786432;            // 8192*512 = 4194304 u16
  u16* Qb  = mfb + 4194304;          // 8192*512 = 4194304 u16
  u16* dyn = Qb + 4194304;

  // per-batch scratch: K(2MB) + Vt(2MB) + S(0.5MB) = 4718592 B
  const size_t fixedB = (size_t)(786432 + 4194304 + 4194304) * 2;
  int CB = 64;
  while (CB > 1 && fixedB + (size_t)CB * 4718592ull > ws_size) CB >>= 1;

  u16* Kc  = dyn;                               // [CB*2048, 512]
  u16* Vtc = Kc + (size_t)CB * 1048576;         // [CB, 512, 2048]
  u16* Sc  = Vtc + (size_t)CB * 1048576;        // [CB, 128, 2048]

  const float scale = 0.044194173824159216f;    // 1/sqrt(512)

  wconv_k<<<768, 256, 0, stream>>>(Wq, Wk, Wv, Wb);
  cvt_k<<<2048, 256, 0, stream>>>(mf, mfb);     // 4194304 elems

  // Q projection: M=8192, N=512, K=512, bf16 A
  gemm_k<0, 0, 0><<<dim3(4, 64, 1), 256, 0, stream>>>(
      mfb, Wb, Qb, nullptr, nullptr, 512, 0, 0, 0, 0, 512, 1.f);

  for (int bc = 0; bc < 64; bc += CB) {
    const float* xc = x + (long)bc * 2048 * 512;
    // fused K+V projection: f32 A direct, N=1024 (0-511 -> K, 512-1023 -> V^T)
    gemm_k<1, 1, 1><<<dim3(8, CB * 16, 1), 256, 0, stream>>>(
        xc, Wb + 262144, Kc, Vtc, nullptr, 512, 0, 0, 0, 0, 512, 1.f);
    // scores: S[q,kv] = (Q K^T)*scale - (1-mask)*1e10  (bf16)
    gemm_k<0, 2, 0><<<dim3(16, 1, CB), 256, 0, stream>>>(
        Qb + (long)bc * 65536, Kc, Sc, nullptr, mask + (long)bc * 2048,
        512, 65536, 1048576, 262144, 2048, 2048, scale);
    softmax_k<<<CB * 128, 256, 0, stream>>>(Sc);
    // PV: out = relu(P V^T), K=2048, f32 out
    gemm_k<0, 3, 0><<<dim3(4, 1, CB), 256, 0, stream>>>(
        Sc, Vtc, out + (long)bc * 65536, nullptr, nullptr,
        2048, 262144, 1048576, 65536, 0, 512, 1.f);
  }
}